// Round 10
// baseline (99.419 us; speedup 1.0000x reference)
//
#include <hip/hip_runtime.h>

#define BB 8
#define NN 2048
#define VV 64
#define CHK 64             // rows per block
#define NC (NN / CHK)      // 32 chunks per batch
#define NBLK (BB * NC)     // 256 blocks == CU count

// ---------------------------------------------------------------------------
// Inputs fp32, output fp32 (verified R4-R9, absmax 7.8e-3).
//
// Closed form: after causal masking row i has two non-structural logits:
//   col 0   : c_i = (h_i.qk_bos)*(h_0.qk_direction)
//   col i-1 : s_i = h_i.qk_previous   (merged into col 0 when i==1)
// remaining (i-1) allowed cols have logit 0, value h_j*wv. With
// S_i = sum_{j=1..i} h_j, m = max(c,s,0):
//   Z   = e^{c-m} + e^{s-m} + (i-1) e^{-m}
//   out = [e^{c-m} vbos + (e^{s-m}-e^{-m}) h_{i-1} wv + e^{-m} S_i wv] / Z
// Row 0: vbos.  Row 1: 2-way softmax over {c_1+s_1, 0}.
//
// R9 lesson: total is ~93us harness floor + ~5-8us kernel. Last lever:
// A4 prefix-recompute was 512 scalar stride-256B loads on the worst wave;
// now 128 coalesced float4 loads (lane l owns channel-quartet 4*(l%16),
// rows l/16+4j) with an LDS transpose-combine in phase C.
// ---------------------------------------------------------------------------

__global__ __launch_bounds__(256) void attn_one(
    const float* __restrict__ h,
    const float* __restrict__ wv_bos,
    const float* __restrict__ wv,
    const float* __restrict__ wo_w,
    const float* __restrict__ qk_direction,
    const float* __restrict__ qk_bos,
    const float* __restrict__ qk_previous,
    float* __restrict__ out)
{
  const int tid  = threadIdx.x;
  const int lane = tid & 63;
  const int w    = tid >> 6;        // wave 0..3
  const int bid  = blockIdx.x;
  const int b    = bid >> 5;        // NC == 32
  const int g    = bid & 31;
  const int r0   = g * CHK;

  __shared__ float  tf[CHK * VV];     // 16 KB own tile
  __shared__ float  s_wo[VV * 65];    // wo_w, pad-65 (2-way alias = free)
  __shared__ float  s_wvb[VV];
  __shared__ float  s_pdc[4][CHK];    // dot partials (c) per channel-quarter
  __shared__ float  s_pds[4][CHK];    // dot partials (s)
  __shared__ float4 s_pre4[4][VV];    // vec4 prefix partials (4 KB)
  __shared__ float  s_sub[4][VV];     // per-wave 16-row sums
  __shared__ float2 s_dots[CHK];      // combined per-row (c,s)
  __shared__ float  s_vb[VV];         // vbos
  __shared__ float  s_db;             // h[b,0,:].qk_direction

  const float* hb = h + (size_t)b * NN * VV;

  // ---- A1: stage own 64x64 tile -> LDS (coalesced float4) ----
  {
    const float4* src = (const float4*)(hb + (size_t)r0 * VV);
    float4* dst = (float4*)tf;
#pragma unroll
    for (int i = 0; i < 4; i++) dst[tid + 256 * i] = src[tid + 256 * i];
  }
  // ---- A2: stage wo_w (16 KB) into padded LDS; stage wv_bos ----
  {
#pragma unroll
    for (int i = 0; i < 16; i++) {
      const int idx = tid + 256 * i;         // = c*64 + k, coalesced
      s_wo[(idx >> 6) * 65 + (idx & 63)] = wo_w[idx];
    }
    if (tid < VV) s_wvb[tid] = wv_bos[tid];
  }
  // ---- A3: dot partials. wave w = channels 16w..16w+15, lane = row ----
  {
    const float* qb = qk_bos + 16 * w;       // wave-uniform -> scalar loads
    const float* qp = qk_previous + 16 * w;
    const float4* rp = (const float4*)(hb + (size_t)(r0 + lane) * VV + 16 * w);
    float cd = 0.f, sd = 0.f;
#pragma unroll
    for (int j = 0; j < 4; j++) {
      const float4 q = rp[j];
      cd = fmaf(q.x, qb[4*j+0], cd); sd = fmaf(q.x, qp[4*j+0], sd);
      cd = fmaf(q.y, qb[4*j+1], cd); sd = fmaf(q.y, qp[4*j+1], sd);
      cd = fmaf(q.z, qb[4*j+2], cd); sd = fmaf(q.z, qp[4*j+2], sd);
      cd = fmaf(q.w, qb[4*j+3], cd); sd = fmaf(q.w, qp[4*j+3], sd);
    }
    s_pdc[w][lane] = cd;
    s_pds[w][lane] = sd;
  }
  // ---- A4: prefix partials, vectorized. Wave w sums chunks k=w,w+4,..<g
  //      as float4: lane l reads positions l+64j (j=0..15) of each chunk
  //      -> lane l owns channels 4*(l%16)..+3 over rows l/16+4j. ----
  {
    float4 a0 = {0,0,0,0}, a1 = {0,0,0,0}, a2 = {0,0,0,0}, a3 = {0,0,0,0};
    const float4* h4 = (const float4*)hb;
    for (int k = w; k < g; k += 4) {
      const float4* cp = h4 + (size_t)k * (CHK * VV / 4) + lane;
#pragma unroll
      for (int j = 0; j < 16; j += 4) {
        const float4 q0 = cp[(j+0) * 64];
        const float4 q1 = cp[(j+1) * 64];
        const float4 q2 = cp[(j+2) * 64];
        const float4 q3 = cp[(j+3) * 64];
        a0.x += q0.x; a0.y += q0.y; a0.z += q0.z; a0.w += q0.w;
        a1.x += q1.x; a1.y += q1.y; a1.z += q1.z; a1.w += q1.w;
        a2.x += q2.x; a2.y += q2.y; a2.z += q2.z; a2.w += q2.w;
        a3.x += q3.x; a3.y += q3.y; a3.z += q3.z; a3.w += q3.w;
      }
    }
    float4 acc;
    acc.x = (a0.x + a1.x) + (a2.x + a3.x);
    acc.y = (a0.y + a1.y) + (a2.y + a3.y);
    acc.z = (a0.z + a1.z) + (a2.z + a3.z);
    acc.w = (a0.w + a1.w) + (a2.w + a3.w);
    s_pre4[w][lane] = acc;
  }
  // prev row for wave 0 (g>0); h0 for exclusion/db (g>0 from global)
  float prev0 = 0.f;
  if (w == 0 && g > 0) prev0 = hb[(size_t)(r0 - 1) * VV + lane];
  float h0v = (g > 0) ? hb[lane] : 0.f;

  __syncthreads();
  if (g == 0) h0v = tf[lane];                // row 0 from own tile

  // ---- B1: own rows -> registers + per-wave sums ----
  float hv[16];
  const int rbase = r0 + 16 * w;
  {
    float s = 0.f;
#pragma unroll
    for (int t = 0; t < 16; t++) {
      hv[t] = tf[(16 * w + t) * VV + lane];  // 2-way bank alias: free
      s += hv[t];
    }
    s_sub[w][lane] = s;
  }
  // ---- B2: per-wave side jobs ----
  if (w == 0) {            // combine dots
    const float cd = s_pdc[0][lane] + s_pdc[1][lane] + s_pdc[2][lane] + s_pdc[3][lane];
    const float sd = s_pds[0][lane] + s_pds[1][lane] + s_pds[2][lane] + s_pds[3][lane];
    s_dots[lane] = make_float2(cd, sd);
  } else if (w == 1) {     // db = h[b,0,:].qk_direction
    float p = h0v * qk_direction[lane];
#pragma unroll
    for (int off = 32; off; off >>= 1) p += __shfl_xor(p, off, 64);
    if (lane == 0) s_db = p;
  } else if (w == 3) {     // vbos: lane = out-channel, serial k over LDS
    const float* row = s_wo + lane * 65;
    float v0=0.f,v1=0.f,v2=0.f,v3=0.f;
#pragma unroll
    for (int k = 0; k < VV; k += 4) {
      v0 = fmaf(row[k+0], s_wvb[k+0], v0);
      v1 = fmaf(row[k+1], s_wvb[k+1], v1);
      v2 = fmaf(row[k+2], s_wvb[k+2], v2);
      v3 = fmaf(row[k+3], s_wvb[k+3], v3);
    }
    s_vb[lane] = (v0+v1) + (v2+v3);
  }
  __syncthreads();

  // ---- C: emit 16 rows per wave, closed form, registers + LDS only ----
  {
    // prefix base: combine vec4 partials. For channel ch, contributions
    // live at float-index 256*w' + 64*r + ch (w',r in 0..3) -- consecutive
    // across lanes, conflict-free.
    const float* pf = (const float*)s_pre4;
    float b0 = 0.f, b1 = 0.f, b2 = 0.f, b3 = 0.f;
#pragma unroll
    for (int w4 = 0; w4 < 4; w4++) {
      b0 += pf[w4 * 256 +   0 + lane];
      b1 += pf[w4 * 256 +  64 + lane];
      b2 += pf[w4 * 256 + 128 + lane];
      b3 += pf[w4 * 256 + 192 + lane];
    }
    float S = (b0 + b1) + (b2 + b3);
    for (int k = 0; k < w; k++) S += s_sub[k][lane];
    if (g > 0 || w > 0) S -= h0v;            // row 0 excluded from prefix

    const float vb  = s_vb[lane];
    const float dbb = s_db;
    const float wvc = wv[lane];
    float prev = (w > 0) ? tf[(16 * w - 1) * VV + lane] : prev0;
    float* op = out + ((size_t)b * NN + rbase) * VV + lane;

#pragma unroll
    for (int t = 0; t < 16; t++) {
      const int ri = rbase + t;
      const float hvt = hv[t];
      if (ri > 0) S += hvt;                  // S_i = sum_{j=1..i} h_j
      const float2 d = s_dots[16 * w + t];   // uniform LDS -> broadcast
      const float ci = d.x * dbb;
      const float si = d.y;
      float o;
      if (ri == 0) {
        o = vb;
      } else if (ri == 1) {
        const float l  = ci + si;            // merged logit at col 0
        const float m  = fmaxf(l, 0.f);
        const float e0 = __expf(l - m);
        const float e1 = __expf(-m);
        o = (e0 * vb + e1 * hvt * wvc) / (e0 + e1);
      } else {
        const float m  = fmaxf(fmaxf(ci, si), 0.f);
        const float e0 = __expf(ci - m);
        const float es = __expf(si - m);
        const float ew = __expf(-m);
        const float Z  = e0 + es + (float)(ri - 1) * ew;
        o = (e0 * vb + (es - ew) * prev * wvc + ew * S * wvc) / Z;
      }
      op[(size_t)t * VV] = o;
      prev = hvt;
    }
  }
}

extern "C" void kernel_launch(void* const* d_in, const int* in_sizes, int n_in,
                              void* d_out, int out_size, void* d_ws, size_t ws_size,
                              hipStream_t stream)
{
  const float* h       = (const float*)d_in[0];
  // d_in[1] = mask_one, d_in[2] = mask_zero — structural (causal), unused
  const float* wv_bos  = (const float*)d_in[3];
  const float* wv      = (const float*)d_in[4];
  const float* wo_w    = (const float*)d_in[5];
  const float* qk_dir  = (const float*)d_in[6];
  const float* qk_bos  = (const float*)d_in[7];
  const float* qk_prev = (const float*)d_in[8];
  float* outp = (float*)d_out;

  hipLaunchKernelGGL(attn_one, dim3(NBLK), dim3(256), 0, stream,
                     h, wv_bos, wv, wo_w, qk_dir, qk_bos, qk_prev, outp);
}